// Round 1
// baseline (1785.361 us; speedup 1.0000x reference)
//
#include <hip/hip_runtime.h>
#include <cstdint>
#include <cstddef>

namespace {

constexpr int TS  = 512;   // timesteps
constexpr int BB  = 1024;  // batch
constexpr int IND = 32;    // input dim
constexpr int H0D = 128;   // layer0 hidden
constexpr int H1D = 64;    // layer1 hidden
constexpr int GS0 = 644;   // LDS row stride (floats): 512 gates + 128 s0x + 4 pad
constexpr int GS1 = 324;   // 256 gates + 64 s1x + 4 pad

typedef float f32x4 __attribute__((ext_vector_type(4)));
typedef float f32x2 __attribute__((ext_vector_type(2)));
typedef __bf16 bf16x8 __attribute__((ext_vector_type(8)));
typedef short s16x8 __attribute__((ext_vector_type(8)));
typedef short s16x4 __attribute__((ext_vector_type(4)));
typedef short s16x2 __attribute__((ext_vector_type(2)));

__device__ __forceinline__ short f2bf(float f) {
    union { float f; unsigned u; } v; v.f = f;
    unsigned r = v.u + 0x7FFFu + ((v.u >> 16) & 1u);  // RNE
    return (short)(r >> 16);
}
__device__ __forceinline__ float sigm(float z) { return 1.0f / (1.0f + __expf(-z)); }
// tanh via exp, inf-safe at both ends: 1 - 2/(e^{2z}+1)
__device__ __forceinline__ float tanh_f(float z) {
    return 1.0f - 2.0f / (__expf(2.0f * z) + 1.0f);
}
__device__ __forceinline__ s16x8 cvt8(float4 a, float4 b) {
    s16x8 r;
    r[0]=f2bf(a.x); r[1]=f2bf(a.y); r[2]=f2bf(a.z); r[3]=f2bf(a.w);
    r[4]=f2bf(b.x); r[5]=f2bf(b.y); r[6]=f2bf(b.z); r[7]=f2bf(b.w);
    return r;
}
__device__ __forceinline__ s16x8 ld8(const float* p) {
    float4 a = *(const float4*)p;
    float4 b = *(const float4*)(p + 4);
    return cvt8(a, b);
}
__device__ __forceinline__ f32x4 mfma16(s16x8 a, s16x8 b, f32x4 c) {
    return __builtin_amdgcn_mfma_f32_16x16x32_bf16(
        __builtin_bit_cast(bf16x8, a), __builtin_bit_cast(bf16x8, b), c, 0, 0, 0);
}

// One workgroup = 16 batch rows for ALL 512 steps. 8 waves, 512 threads.
// Weights live in VGPRs as pre-swizzled bf16 MFMA B-fragments (loaded once).
// Per step: P1 mfma gates0 -> P2 elementwise L0 -> P3 mfma gates1 -> P4 elementwise L1.
__global__ __launch_bounds__(512) void resid_lstm(
    const float* __restrict__ x,
    const float* __restrict__ h0i, const float* __restrict__ c0i,
    const float* __restrict__ h1i, const float* __restrict__ c1i,
    const float* __restrict__ Wih0, const float* __restrict__ Whh0,
    const float* __restrict__ bih0, const float* __restrict__ bhh0,
    const float* __restrict__ Ws0,  const float* __restrict__ bs0v,
    const float* __restrict__ Wih1, const float* __restrict__ Whh1,
    const float* __restrict__ bih1, const float* __restrict__ bhh1,
    const float* __restrict__ Ws1,  const float* __restrict__ bs1v,
    float* __restrict__ out)
{
    const int tid  = threadIdx.x;
    const int lane = tid & 63;
    const int wave = tid >> 6;        // 0..7
    const int fr   = lane & 15;       // fragment row (A) / out-col (B,C)
    const int fk   = lane >> 4;       // k-group 0..3 (8 consecutive k each)
    const int row0 = blockIdx.x << 4; // batch row base of this WG

    __shared__ __align__(16) float g0e[16 * GS0];            // gates0 + s0x (fp32)
    __shared__ __align__(16) float g1e[16 * GS1];            // gates1 + s1x (fp32)
    __shared__ __align__(16) unsigned short h0s[16 * 128];   // h0 state, bf16, swizzled
    __shared__ __align__(16) unsigned short i1s[16 * 128];   // clip(h0), bf16, swizzled
    __shared__ __align__(16) unsigned short h1s[16 * 64];    // h1 state, bf16, swizzled

    // ---------------- load weight fragments once (bf16) ----------------
    // B-frag for 16x16x32: lane holds W[tile*16 + fr][ks*32 + fk*8 + i], i=0..7
    s16x8 wh0[4][4], wi0[4], ws0f;
    #pragma unroll
    for (int j = 0; j < 4; ++j) {
        const int outr = (wave * 4 + j) * 16 + fr;
        #pragma unroll
        for (int ks = 0; ks < 4; ++ks)
            wh0[j][ks] = ld8(Whh0 + outr * H0D + ks * 32 + fk * 8);
        wi0[j] = ld8(Wih0 + outr * IND + fk * 8);
    }
    ws0f = ld8(Ws0 + (wave * 16 + fr) * IND + fk * 8);

    s16x8 wi1[2][4], wh1[2][2];
    #pragma unroll
    for (int j = 0; j < 2; ++j) {
        const int outr = (wave * 2 + j) * 16 + fr;
        #pragma unroll
        for (int ks = 0; ks < 4; ++ks)
            wi1[j][ks] = ld8(Wih1 + outr * H0D + ks * 32 + fk * 8);
        #pragma unroll
        for (int ks = 0; ks < 2; ++ks)
            wh1[j][ks] = ld8(Whh1 + outr * H1D + ks * 32 + fk * 8);
    }
    s16x8 ws1f[4];
    if (wave >= 4) {
        const int outr = ((wave - 4) * 16 + fr);
        #pragma unroll
        for (int ks = 0; ks < 4; ++ks)
            ws1f[ks] = ld8(Ws1 + outr * H0D + ks * 32 + fk * 8);
    }

    // biases folded into MFMA C-init (constant per output column fr)
    float bj0[4], bj1[2], bss0, bss1 = 0.f;
    #pragma unroll
    for (int j = 0; j < 4; ++j) {
        const int o = (wave * 4 + j) * 16 + fr;
        bj0[j] = bih0[o] + bhh0[o];
    }
    #pragma unroll
    for (int j = 0; j < 2; ++j) {
        const int o = (wave * 2 + j) * 16 + fr;
        bj1[j] = bih1[o] + bhh1[o];
    }
    bss0 = bs0v[wave * 16 + fr];
    if (wave >= 4) bss1 = bs1v[(wave - 4) * 16 + fr];

    // ---------------- updater-thread mapping ----------------
    const int row2 = tid >> 5;       // 0..15
    const int j2   = tid & 31;
    const int u0   = j2 * 4;         // 4 consecutive layer0 hidden units
    const int u1   = j2 * 2;         // 2 consecutive layer1 hidden units

    float c0r[4], c1r[2];
    #pragma unroll
    for (int q = 0; q < 4; ++q) c0r[q] = c0i[(row0 + row2) * H0D + u0 + q];
    #pragma unroll
    for (int q = 0; q < 2; ++q) c1r[q] = c1i[(row0 + row2) * H1D + u1 + q];

    // initial h states into swizzled bf16 LDS tiles
    {
        s16x4 hv;
        #pragma unroll
        for (int q = 0; q < 4; ++q) hv[q] = f2bf(h0i[(row0 + row2) * H0D + u0 + q]);
        const int g16 = (j2 >> 1) ^ (row2 & 7);
        *(s16x4*)&h0s[row2 * 128 + (g16 << 3) + (j2 & 1) * 4] = hv;

        s16x2 h1v;
        #pragma unroll
        for (int q = 0; q < 2; ++q) h1v[q] = f2bf(h1i[(row0 + row2) * H1D + u1 + q]);
        const int g8 = (j2 >> 2) ^ (row2 & 7);
        *(s16x2*)&h1s[row2 * 64 + (g8 << 3) + (j2 & 3) * 2] = h1v;
    }
    __syncthreads();

    const size_t YS  = (size_t)TS * BB * H1D;
    const size_t H0O = YS;
    const size_t C0O = H0O + (size_t)BB * H0D;
    const size_t H1O = C0O + (size_t)BB * H0D;
    const size_t C1O = H1O + (size_t)BB * H1D;

    // x prefetch (one step ahead)
    float4 xa = *(const float4*)(x + ((size_t)0 * BB + row0 + fr) * IND + fk * 8);
    float4 xb = *(const float4*)(x + ((size_t)0 * BB + row0 + fr) * IND + fk * 8 + 4);

    #pragma unroll 1
    for (int t = 0; t < TS; ++t) {
        // ================= Phase 1: layer0 gates =================
        s16x8 xf = cvt8(xa, xb);
        {   // prefetch x for t+1 (latency hides under P2..P4)
            const int tn = (t + 1 < TS) ? t + 1 : t;
            const float* xp = x + ((size_t)tn * BB + row0 + fr) * IND + fk * 8;
            xa = *(const float4*)xp;
            xb = *(const float4*)(xp + 4);
        }
        s16x8 hf[4];
        #pragma unroll
        for (int ks = 0; ks < 4; ++ks)
            hf[ks] = *(const s16x8*)&h0s[fr * 128 + ((((ks * 4) + fk) ^ (fr & 7)) << 3)];

        #pragma unroll
        for (int j = 0; j < 4; ++j) {
            f32x4 a = {bj0[j], bj0[j], bj0[j], bj0[j]};
            a = mfma16(xf, wi0[j], a);
            #pragma unroll
            for (int ks = 0; ks < 4; ++ks) a = mfma16(hf[ks], wh0[j][ks], a);
            const int ob = (wave * 4 + j) * 16 + fr;
            #pragma unroll
            for (int q = 0; q < 4; ++q) g0e[(fk * 4 + q) * GS0 + ob] = a[q];
        }
        {
            f32x4 a = {bss0, bss0, bss0, bss0};
            a = mfma16(xf, ws0f, a);
            const int ob = 512 + wave * 16 + fr;
            #pragma unroll
            for (int q = 0; q < 4; ++q) g0e[(fk * 4 + q) * GS0 + ob] = a[q];
        }
        __syncthreads();

        // ================= Phase 2: layer0 elementwise =================
        {
            const int base = row2 * GS0 + u0;
            f32x4 gi = *(const f32x4*)&g0e[base];
            f32x4 gf = *(const f32x4*)&g0e[base + 128];
            f32x4 gg = *(const f32x4*)&g0e[base + 256];
            f32x4 go = *(const f32x4*)&g0e[base + 384];
            f32x4 sx = *(const f32x4*)&g0e[base + 512];
            float h0n[4];
            s16x4 hb, ib;
            #pragma unroll
            for (int q = 0; q < 4; ++q) {
                float iv = sigm(gi[q]);
                float fv = sigm(gf[q]);
                float gv = tanh_f(gg[q]);
                float ov = sigm(go[q]);
                float c  = fv * c0r[q] + iv * gv;
                c0r[q] = c;
                float hn = ov * tanh_f(c) + sx[q];  // s0x includes bs0
                h0n[q] = hn;
                hb[q] = f2bf(hn);                                  // pre-clip state
                ib[q] = f2bf(fminf(fmaxf(hn, -10.f), 10.f));       // layer1 input
            }
            const int g16 = (j2 >> 1) ^ (row2 & 7);
            const int idx = row2 * 128 + (g16 << 3) + (j2 & 1) * 4;
            *(s16x4*)&h0s[idx] = hb;
            *(s16x4*)&i1s[idx] = ib;
            if (t == TS - 1) {
                float4 hv = {h0n[0], h0n[1], h0n[2], h0n[3]};
                *(float4*)&out[H0O + (size_t)(row0 + row2) * H0D + u0] = hv;
                float4 cv = {c0r[0], c0r[1], c0r[2], c0r[3]};
                *(float4*)&out[C0O + (size_t)(row0 + row2) * H0D + u0] = cv;
            }
        }
        __syncthreads();

        // ================= Phase 3: layer1 gates =================
        s16x8 pf[4];
        #pragma unroll
        for (int ks = 0; ks < 4; ++ks)
            pf[ks] = *(const s16x8*)&i1s[fr * 128 + ((((ks * 4) + fk) ^ (fr & 7)) << 3)];
        s16x8 h1f[2];
        #pragma unroll
        for (int ks = 0; ks < 2; ++ks)
            h1f[ks] = *(const s16x8*)&h1s[fr * 64 + ((((ks * 4) + fk) ^ (fr & 7)) << 3)];

        #pragma unroll
        for (int j = 0; j < 2; ++j) {
            f32x4 a = {bj1[j], bj1[j], bj1[j], bj1[j]};
            #pragma unroll
            for (int ks = 0; ks < 4; ++ks) a = mfma16(pf[ks], wi1[j][ks], a);
            #pragma unroll
            for (int ks = 0; ks < 2; ++ks) a = mfma16(h1f[ks], wh1[j][ks], a);
            const int ob = (wave * 2 + j) * 16 + fr;
            #pragma unroll
            for (int q = 0; q < 4; ++q) g1e[(fk * 4 + q) * GS1 + ob] = a[q];
        }
        if (wave >= 4) {
            f32x4 a = {bss1, bss1, bss1, bss1};
            #pragma unroll
            for (int ks = 0; ks < 4; ++ks) a = mfma16(pf[ks], ws1f[ks], a);
            const int ob = 256 + (wave - 4) * 16 + fr;
            #pragma unroll
            for (int q = 0; q < 4; ++q) g1e[(fk * 4 + q) * GS1 + ob] = a[q];
        }
        __syncthreads();

        // ================= Phase 4: layer1 elementwise =================
        {
            const int base = row2 * GS1 + u1;
            f32x2 gi = *(const f32x2*)&g1e[base];
            f32x2 gf = *(const f32x2*)&g1e[base + 64];
            f32x2 gg = *(const f32x2*)&g1e[base + 128];
            f32x2 go = *(const f32x2*)&g1e[base + 192];
            f32x2 sx = *(const f32x2*)&g1e[base + 256];
            float h1n[2], yv[2];
            #pragma unroll
            for (int q = 0; q < 2; ++q) {
                float iv = sigm(gi[q]);
                float fv = sigm(gf[q]);
                float gv = tanh_f(gg[q]);
                float ov = sigm(go[q]);
                float c  = fv * c1r[q] + iv * gv;
                c1r[q] = c;
                float hn = ov * tanh_f(c) + sx[q];  // s1x includes bs1
                h1n[q] = hn;
                yv[q] = fminf(fmaxf(hn, -10.f), 10.f);
            }
            f32x2 yo = {yv[0], yv[1]};
            *(f32x2*)&out[((size_t)t * BB + row0 + row2) * H1D + u1] = yo;
            s16x2 hb; hb[0] = f2bf(h1n[0]); hb[1] = f2bf(h1n[1]);
            const int g8 = (j2 >> 2) ^ (row2 & 7);
            *(s16x2*)&h1s[row2 * 64 + (g8 << 3) + (j2 & 3) * 2] = hb;
            if (t == TS - 1) {
                f32x2 hv = {h1n[0], h1n[1]};
                *(f32x2*)&out[H1O + (size_t)(row0 + row2) * H1D + u1] = hv;
                f32x2 cv = {c1r[0], c1r[1]};
                *(f32x2*)&out[C1O + (size_t)(row0 + row2) * H1D + u1] = cv;
            }
        }
        __syncthreads();
    }
}

} // namespace

extern "C" void kernel_launch(void* const* d_in, const int* in_sizes, int n_in,
                              void* d_out, int out_size, void* d_ws, size_t ws_size,
                              hipStream_t stream) {
    (void)in_sizes; (void)n_in; (void)d_ws; (void)ws_size; (void)out_size;
    const float* x    = (const float*)d_in[0];
    const float* h0i  = (const float*)d_in[1];
    const float* c0i  = (const float*)d_in[2];
    const float* h1i  = (const float*)d_in[3];
    const float* c1i  = (const float*)d_in[4];
    const float* Wih0 = (const float*)d_in[5];
    const float* Whh0 = (const float*)d_in[6];
    const float* bih0 = (const float*)d_in[7];
    const float* bhh0 = (const float*)d_in[8];
    const float* Ws0  = (const float*)d_in[9];
    const float* bs0  = (const float*)d_in[10];
    const float* Wih1 = (const float*)d_in[11];
    const float* Whh1 = (const float*)d_in[12];
    const float* bih1 = (const float*)d_in[13];
    const float* bhh1 = (const float*)d_in[14];
    const float* Ws1  = (const float*)d_in[15];
    const float* bs1  = (const float*)d_in[16];

    resid_lstm<<<dim3(BB / 16), dim3(512), 0, stream>>>(
        x, h0i, c0i, h1i, c1i,
        Wih0, Whh0, bih0, bhh0, Ws0, bs0,
        Wih1, Whh1, bih1, bhh1, Ws1, bs1,
        (float*)d_out);
}

// Round 2
// 1052.480 us; speedup vs baseline: 1.6963x; 1.6963x over previous
//
#include <hip/hip_runtime.h>
#include <cstdint>
#include <cstddef>

namespace {

constexpr int TS  = 512;   // timesteps
constexpr int BB  = 1024;  // batch
constexpr int IND = 32;    // input dim
constexpr int H0D = 128;   // layer0 hidden
constexpr int H1D = 64;    // layer1 hidden

typedef float f32x4 __attribute__((ext_vector_type(4)));
typedef __bf16 bf16x8 __attribute__((ext_vector_type(8)));
typedef short s16x8 __attribute__((ext_vector_type(8)));

__device__ __forceinline__ float rcpf(float x) {
    float r; asm("v_rcp_f32 %0, %1" : "=v"(r) : "v"(x)); return r;
}
__device__ __forceinline__ unsigned pkbf(float lo, float hi) {
    unsigned r; asm("v_cvt_pk_bf16_f32 %0, %1, %2" : "=v"(r) : "v"(lo), "v"(hi)); return r;
}
__device__ __forceinline__ short f2bf(float f) {
    union { float f; unsigned u; } v; v.f = f;
    unsigned r = v.u + 0x7FFFu + ((v.u >> 16) & 1u);  // RNE
    return (short)(r >> 16);
}
__device__ __forceinline__ float sigm(float z) { return rcpf(1.0f + __expf(-z)); }
__device__ __forceinline__ float tanh_f(float z) {
    return fmaf(-2.0f, rcpf(__expf(2.0f * z) + 1.0f), 1.0f);  // inf-safe both ends
}
__device__ __forceinline__ s16x8 cvt8(float4 a, float4 b) {
    union { unsigned u[4]; s16x8 v; } r;
    r.u[0] = pkbf(a.x, a.y); r.u[1] = pkbf(a.z, a.w);
    r.u[2] = pkbf(b.x, b.y); r.u[3] = pkbf(b.z, b.w);
    return r.v;
}
__device__ __forceinline__ s16x8 ld8(const float* p) {
    float4 a = *(const float4*)p;
    float4 b = *(const float4*)(p + 4);
    return cvt8(a, b);
}
__device__ __forceinline__ f32x4 mfma16(s16x8 a, s16x8 b, f32x4 c) {
    return __builtin_amdgcn_mfma_f32_16x16x32_bf16(
        __builtin_bit_cast(bf16x8, a), __builtin_bit_cast(bf16x8, b), c, 0, 0, 0);
}
// swizzled bf16 state-tile address (W = row width in ushorts: 128 or 64)
__device__ __forceinline__ int haddr(int row, int u, int W) {
    return row * W + ((((u >> 3) ^ (row & 7))) << 3) + (u & 7);
}

// One WG = 16 batch rows, all 512 steps. 8 waves / 512 threads.
// Wave w owns layer0 unit-slice [w*16, w*16+16): all 4 gate tiles + shortcut
//   -> gates & c0 stay in the computing lane's registers (no LDS round-trip).
// Layer1 slice s=w&3 is K-split between wave s (half 0, writes fp32 partials)
//   and wave 4+s (half 1, adds partials, does elementwise, owns c1, stores y).
// 3 barriers/step.
__global__ __launch_bounds__(512, 2) void resid_lstm(
    const float* __restrict__ x,
    const float* __restrict__ h0i, const float* __restrict__ c0i,
    const float* __restrict__ h1i, const float* __restrict__ c1i,
    const float* __restrict__ Wih0, const float* __restrict__ Whh0,
    const float* __restrict__ bih0, const float* __restrict__ bhh0,
    const float* __restrict__ Ws0,  const float* __restrict__ bs0v,
    const float* __restrict__ Wih1, const float* __restrict__ Whh1,
    const float* __restrict__ bih1, const float* __restrict__ bhh1,
    const float* __restrict__ Ws1,  const float* __restrict__ bs1v,
    float* __restrict__ out)
{
    const int tid  = threadIdx.x;
    const int lane = tid & 63;
    const int w    = tid >> 6;        // wave 0..7
    const int fr   = lane & 15;       // A-row (batch) for frags / C-col (unit)
    const int fk   = lane >> 4;       // k-group / C-row group
    const int row0 = blockIdx.x << 4;

    const int u0   = w * 16 + fr;     // layer0 unit owned by this lane
    const int s    = w & 3;           // layer1 slice
    const int half = w >> 2;          // layer1 K-half
    const int u1   = s * 16 + fr;     // layer1 unit
    const bool fin = (half == 1);     // finisher waves 4..7

    __shared__ unsigned short h0s[2][16 * 128];
    __shared__ unsigned short i1s[16 * 128];
    __shared__ unsigned short h1s[2][16 * 64];
    __shared__ __align__(16) float pt[4][5][256];   // [slice][tile][lane*4] partials

    // ---------------- weight fragments (bf16, registers) ----------------
    s16x8 wi0g[4], wh0g[4][4], ws0f, wi1g[4][2], wh1g[4], ws1f[2];
    float bg0[4], bg1[4], bs0r, bs1r;
    #pragma unroll
    for (int g = 0; g < 4; ++g) {
        const int r0 = g * H0D + u0;            // PyTorch gate order i,f,g,o
        wi0g[g] = ld8(Wih0 + r0 * IND + fk * 8);
        #pragma unroll
        for (int ks = 0; ks < 4; ++ks)
            wh0g[g][ks] = ld8(Whh0 + r0 * H0D + ks * 32 + fk * 8);
        bg0[g] = bih0[r0] + bhh0[r0];

        const int r1 = g * H1D + u1;
        #pragma unroll
        for (int k2 = 0; k2 < 2; ++k2)
            wi1g[g][k2] = ld8(Wih1 + r1 * H0D + half * 64 + k2 * 32 + fk * 8);
        wh1g[g] = ld8(Whh1 + r1 * H1D + half * 32 + fk * 8);
        bg1[g] = bih1[r1] + bhh1[r1];
    }
    ws0f = ld8(Ws0 + u0 * IND + fk * 8);
    bs0r = bs0v[u0];
    #pragma unroll
    for (int k2 = 0; k2 < 2; ++k2)
        ws1f[k2] = ld8(Ws1 + u1 * H0D + half * 64 + k2 * 32 + fk * 8);
    bs1r = bs1v[u1];

    // ---------------- c-state (registers) + initial h into LDS ----------------
    float c0r[4], c1r[4];
    #pragma unroll
    for (int q = 0; q < 4; ++q) {
        const int row = fk * 4 + q;
        c0r[q] = c0i[(row0 + row) * H0D + u0];
        h0s[0][haddr(row, u0, 128)] =
            (unsigned short)f2bf(h0i[(row0 + row) * H0D + u0]);
    }
    if (fin) {
        #pragma unroll
        for (int q = 0; q < 4; ++q) {
            const int row = fk * 4 + q;
            c1r[q] = c1i[(row0 + row) * H1D + u1];
            h1s[0][haddr(row, u1, 64)] =
                (unsigned short)f2bf(h1i[(row0 + row) * H1D + u1]);
        }
    } else {
        #pragma unroll
        for (int q = 0; q < 4; ++q) c1r[q] = 0.f;
    }
    __syncthreads();

    const size_t H0O = (size_t)TS * BB * H1D;
    const size_t C0O = H0O + (size_t)BB * H0D;
    const size_t H1O = C0O + (size_t)BB * H0D;
    const size_t C1O = H1O + (size_t)BB * H1D;

    // loop-invariant LDS offsets
    int a0w[4], a1w[4];
    #pragma unroll
    for (int q = 0; q < 4; ++q) {
        a0w[q] = haddr(fk * 4 + q, u0, 128);
        a1w[q] = haddr(fk * 4 + q, u1, 64);
    }
    int hfo[4], pfo[2], h1fo;
    #pragma unroll
    for (int ks = 0; ks < 4; ++ks)
        hfo[ks] = fr * 128 + (((ks * 4 + fk) ^ (fr & 7)) << 3);
    #pragma unroll
    for (int k2 = 0; k2 < 2; ++k2)
        pfo[k2] = fr * 128 + (((half * 8 + k2 * 4 + fk) ^ (fr & 7)) << 3);
    h1fo = fr * 64 + (((half * 4 + fk) ^ (fr & 7)) << 3);

    // x prefetch (one step ahead)
    {
        const float* xp = x + (size_t)(row0 + fr) * IND + fk * 8;
        // loaded below at t=0 via xa/xb
    }
    const float* xp0 = x + (size_t)(row0 + fr) * IND + fk * 8;
    float4 xa = *(const float4*)xp0;
    float4 xb = *(const float4*)(xp0 + 4);

    #pragma unroll 1
    for (int t = 0; t < TS; ++t) {
        const int p = t & 1;
        // ========== Phase A: layer0 gates + elementwise (fused, no barrier) ==========
        s16x8 xf = cvt8(xa, xb);
        {
            const int tn = (t + 1 < TS) ? t + 1 : t;
            const float* xp = x + ((size_t)tn * BB + row0 + fr) * IND + fk * 8;
            xa = *(const float4*)xp;
            xb = *(const float4*)(xp + 4);
        }
        s16x8 hf[4];
        #pragma unroll
        for (int ks = 0; ks < 4; ++ks)
            hf[ks] = *(const s16x8*)&h0s[p][hfo[ks]];

        f32x4 ag[4], as0;
        #pragma unroll
        for (int g = 0; g < 4; ++g) {
            f32x4 a = {bg0[g], bg0[g], bg0[g], bg0[g]};
            a = mfma16(xf, wi0g[g], a);
            #pragma unroll
            for (int ks = 0; ks < 4; ++ks) a = mfma16(hf[ks], wh0g[g][ks], a);
            ag[g] = a;
        }
        {
            f32x4 a = {bs0r, bs0r, bs0r, bs0r};
            as0 = mfma16(xf, ws0f, a);
        }
        float hn[4], iv[4];
        #pragma unroll
        for (int q = 0; q < 4; ++q) {
            float i_ = sigm(ag[0][q]);
            float f_ = sigm(ag[1][q]);
            float g_ = tanh_f(ag[2][q]);
            float o_ = sigm(ag[3][q]);
            float c  = fmaf(f_, c0r[q], i_ * g_);
            c0r[q] = c;
            hn[q] = fmaf(o_, tanh_f(c), as0[q]);      // post-residual, PRE-clip
            iv[q] = fminf(fmaxf(hn[q], -10.f), 10.f); // layer1 input
        }
        {
            unsigned ph01 = pkbf(hn[0], hn[1]), ph23 = pkbf(hn[2], hn[3]);
            unsigned pi01 = pkbf(iv[0], iv[1]), pi23 = pkbf(iv[2], iv[3]);
            unsigned short* hb = &h0s[p ^ 1][0];
            hb[a0w[0]] = (unsigned short)ph01; hb[a0w[1]] = (unsigned short)(ph01 >> 16);
            hb[a0w[2]] = (unsigned short)ph23; hb[a0w[3]] = (unsigned short)(ph23 >> 16);
            i1s[a0w[0]] = (unsigned short)pi01; i1s[a0w[1]] = (unsigned short)(pi01 >> 16);
            i1s[a0w[2]] = (unsigned short)pi23; i1s[a0w[3]] = (unsigned short)(pi23 >> 16);
        }
        if (t == TS - 1) {
            #pragma unroll
            for (int q = 0; q < 4; ++q) {
                out[H0O + (size_t)(row0 + fk * 4 + q) * H0D + u0] = hn[q];
                out[C0O + (size_t)(row0 + fk * 4 + q) * H0D + u0] = c0r[q];
            }
        }
        __syncthreads();   // B1: i1s / h0s[p^1] ready

        // ========== Phase B: layer1 K-half MFMAs ==========
        s16x8 pf[2], h1f;
        #pragma unroll
        for (int k2 = 0; k2 < 2; ++k2)
            pf[k2] = *(const s16x8*)&i1s[pfo[k2]];
        h1f = *(const s16x8*)&h1s[p][h1fo];

        f32x4 a1g[4], a1s;
        #pragma unroll
        for (int g = 0; g < 4; ++g) {
            float bi = fin ? bg1[g] : 0.f;
            f32x4 a = {bi, bi, bi, bi};
            #pragma unroll
            for (int k2 = 0; k2 < 2; ++k2) a = mfma16(pf[k2], wi1g[g][k2], a);
            a = mfma16(h1f, wh1g[g], a);
            a1g[g] = a;
        }
        {
            float bi = fin ? bs1r : 0.f;
            f32x4 a = {bi, bi, bi, bi};
            #pragma unroll
            for (int k2 = 0; k2 < 2; ++k2) a = mfma16(pf[k2], ws1f[k2], a);
            a1s = a;
        }
        if (!fin) {
            #pragma unroll
            for (int g = 0; g < 4; ++g)
                *(f32x4*)&pt[s][g][lane * 4] = a1g[g];
            *(f32x4*)&pt[s][4][lane * 4] = a1s;
        }
        __syncthreads();   // B2: partials ready

        // ========== Phase C: layer1 finish (waves 4..7) ==========
        if (fin) {
            #pragma unroll
            for (int g = 0; g < 4; ++g)
                a1g[g] += *(const f32x4*)&pt[s][g][lane * 4];
            a1s += *(const f32x4*)&pt[s][4][lane * 4];

            float h1n[4];
            #pragma unroll
            for (int q = 0; q < 4; ++q) {
                float i_ = sigm(a1g[0][q]);
                float f_ = sigm(a1g[1][q]);
                float g_ = tanh_f(a1g[2][q]);
                float o_ = sigm(a1g[3][q]);
                float c  = fmaf(f_, c1r[q], i_ * g_);
                c1r[q] = c;
                h1n[q] = fmaf(o_, tanh_f(c), a1s[q]);   // pre-clip state
                float yv = fminf(fmaxf(h1n[q], -10.f), 10.f);
                out[((size_t)t * BB + row0 + fk * 4 + q) * H1D + u1] = yv;
            }
            unsigned q01 = pkbf(h1n[0], h1n[1]), q23 = pkbf(h1n[2], h1n[3]);
            unsigned short* hb = &h1s[p ^ 1][0];
            hb[a1w[0]] = (unsigned short)q01; hb[a1w[1]] = (unsigned short)(q01 >> 16);
            hb[a1w[2]] = (unsigned short)q23; hb[a1w[3]] = (unsigned short)(q23 >> 16);
            if (t == TS - 1) {
                #pragma unroll
                for (int q = 0; q < 4; ++q) {
                    out[H1O + (size_t)(row0 + fk * 4 + q) * H1D + u1] = h1n[q];
                    out[C1O + (size_t)(row0 + fk * 4 + q) * H1D + u1] = c1r[q];
                }
            }
        }
        __syncthreads();   // B3: h1s write done / pt reusable
    }
}

} // namespace

extern "C" void kernel_launch(void* const* d_in, const int* in_sizes, int n_in,
                              void* d_out, int out_size, void* d_ws, size_t ws_size,
                              hipStream_t stream) {
    (void)in_sizes; (void)n_in; (void)d_ws; (void)ws_size; (void)out_size;
    const float* x    = (const float*)d_in[0];
    const float* h0i  = (const float*)d_in[1];
    const float* c0i  = (const float*)d_in[2];
    const float* h1i  = (const float*)d_in[3];
    const float* c1i  = (const float*)d_in[4];
    const float* Wih0 = (const float*)d_in[5];
    const float* Whh0 = (const float*)d_in[6];
    const float* bih0 = (const float*)d_in[7];
    const float* bhh0 = (const float*)d_in[8];
    const float* Ws0  = (const float*)d_in[9];
    const float* bs0  = (const float*)d_in[10];
    const float* Wih1 = (const float*)d_in[11];
    const float* Whh1 = (const float*)d_in[12];
    const float* bih1 = (const float*)d_in[13];
    const float* bhh1 = (const float*)d_in[14];
    const float* Ws1  = (const float*)d_in[15];
    const float* bs1  = (const float*)d_in[16];

    resid_lstm<<<dim3(BB / 16), dim3(512), 0, stream>>>(
        x, h0i, c0i, h1i, c1i,
        Wih0, Whh0, bih0, bhh0, Ws0, bs0,
        Wih1, Whh1, bih1, bhh1, Ws1, bs1,
        (float*)d_out);
}

// Round 5
// 842.947 us; speedup vs baseline: 2.1180x; 1.2486x over previous
//
#include <hip/hip_runtime.h>
#include <cstdint>
#include <cstddef>

namespace {

constexpr int TS  = 512;   // timesteps
constexpr int BB  = 1024;  // batch
constexpr int IND = 32;    // input dim
constexpr int H0D = 128;   // layer0 hidden
constexpr int H1D = 64;    // layer1 hidden
constexpr int RPW = 4;     // batch rows per workgroup -> 256 WGs = all CUs
constexpr int S0  = 132;   // padded LDS row stride (floats) for 128-wide state
constexpr int S1  = 68;    // padded LDS row stride (floats) for 64-wide state

typedef float f32x4 __attribute__((ext_vector_type(4)));
typedef __bf16 bf16x8 __attribute__((ext_vector_type(8)));

__device__ __forceinline__ float rcpf(float x) {
    float r; asm("v_rcp_f32 %0, %1" : "=v"(r) : "v"(x)); return r;
}
__device__ __forceinline__ float sigm(float z) { return rcpf(1.0f + __expf(-z)); }
__device__ __forceinline__ float tanh_f(float z) {
    return fmaf(-2.0f, rcpf(__expf(2.0f * z) + 1.0f), 1.0f);  // inf-safe both ends
}
__device__ __forceinline__ bf16x8 cvt8(f32x4 a, f32x4 b) {
    bf16x8 r;
    r[0] = (__bf16)a[0]; r[1] = (__bf16)a[1]; r[2] = (__bf16)a[2]; r[3] = (__bf16)a[3];
    r[4] = (__bf16)b[0]; r[5] = (__bf16)b[1]; r[6] = (__bf16)b[2]; r[7] = (__bf16)b[3];
    return r;
}
__device__ __forceinline__ bf16x8 ld8(const float* p) {
    f32x4 a = *(const f32x4*)p;
    f32x4 b = *(const f32x4*)(p + 4);
    return cvt8(a, b);
}
__device__ __forceinline__ f32x4 mfma16(bf16x8 a, bf16x8 b, f32x4 c) {
    return __builtin_amdgcn_mfma_f32_16x16x32_bf16(a, b, c, 0, 0, 0);
}

// 256 WGs x 4 batch rows, 8 waves. NO SKEW (bisection of R3/R4 failure):
// phase 1: waves 0-3 do layer0 (2 slices each) for step t; barrier;
// phase 2: waves 4-7 do layer1 full-K for the SAME step t; barrier.
// A-tiles duplicate each batch row x4 (A row r = batch r>>2); C reg 0 of
// lane (fk,fr) = batch fk, unit <tile>+fr (mapping verified in R1/R2).
__global__ __launch_bounds__(512, 2) void resid_lstm(
    const float* __restrict__ x,
    const float* __restrict__ h0i, const float* __restrict__ c0i,
    const float* __restrict__ h1i, const float* __restrict__ c1i,
    const float* __restrict__ Wih0, const float* __restrict__ Whh0,
    const float* __restrict__ bih0, const float* __restrict__ bhh0,
    const float* __restrict__ Ws0,  const float* __restrict__ bs0v,
    const float* __restrict__ Wih1, const float* __restrict__ Whh1,
    const float* __restrict__ bih1, const float* __restrict__ bhh1,
    const float* __restrict__ Ws1,  const float* __restrict__ bs1v,
    float* __restrict__ out)
{
    const int tid  = threadIdx.x;
    const int lane = tid & 63;
    const int w    = tid >> 6;        // wave 0..7
    const int fr   = lane & 15;       // A-row index within tile / C col (unit)
    const int fk   = lane >> 4;       // k-group; also this lane's batch row
    const int row0 = blockIdx.x * RPW;
    const bool prod = (w < 4);

    __shared__ __align__(16) float h0f[2][RPW][S0];   // h0 state (fp32)
    __shared__ __align__(16) float i1f[2][RPW][S0];   // clip(h0) (fp32)
    __shared__ __align__(16) float h1q[2][RPW][S1];   // h1 state (fp32)

    // zero ALL LDS first (separate barrier so init writes can't race it)
    for (int i = tid; i < 2 * RPW * S0; i += 512) {
        (&h0f[0][0][0])[i] = 0.f;
        (&i1f[0][0][0])[i] = 0.f;
    }
    for (int i = tid; i < 2 * RPW * S1; i += 512)
        (&h1q[0][0][0])[i] = 0.f;
    __syncthreads();

    bf16x8 WF[42];    // producer: 42 frags (2 slices x (4 gates x 5 + ws0));
                      // consumer: 28 frags (4 gates x 6 + ws1 x 4)
    float BZ[10];     // folded biases
    float CS[2];      // c-state: producer c0[slice 0,1]; consumer c1 in CS[0]
    CS[0] = 0.f; CS[1] = 0.f;

    if (prod) {
        #pragma unroll
        for (int sl = 0; sl < 2; ++sl) {
            const int u = (w + 4*sl)*16 + fr;
            #pragma unroll
            for (int g = 0; g < 4; ++g) {
                const int r0 = g*H0D + u;             // gate order i,f,g,o
                WF[sl*21 + g*5] = ld8(Wih0 + r0*IND + fk*8);
                #pragma unroll
                for (int ks = 0; ks < 4; ++ks)
                    WF[sl*21 + g*5 + 1 + ks] = ld8(Whh0 + r0*H0D + ks*32 + fk*8);
                BZ[sl*5 + g] = bih0[r0] + bhh0[r0];
            }
            WF[sl*21 + 20] = ld8(Ws0 + u*IND + fk*8);
            BZ[sl*5 + 4] = bs0v[u];
            CS[sl] = c0i[(size_t)(row0 + fk)*H0D + u];
        }
    } else {
        const int u1 = (w - 4)*16 + fr;
        #pragma unroll
        for (int g = 0; g < 4; ++g) {
            const int r1 = g*H1D + u1;
            #pragma unroll
            for (int ks = 0; ks < 4; ++ks)
                WF[g*6 + ks] = ld8(Wih1 + r1*H0D + ks*32 + fk*8);
            #pragma unroll
            for (int k2 = 0; k2 < 2; ++k2)
                WF[g*6 + 4 + k2] = ld8(Whh1 + r1*H1D + k2*32 + fk*8);
            BZ[g] = bih1[r1] + bhh1[r1];
        }
        #pragma unroll
        for (int ks = 0; ks < 4; ++ks)
            WF[24 + ks] = ld8(Ws1 + u1*H0D + ks*32 + fk*8);
        BZ[4] = bs1v[u1];
        CS[0] = c1i[(size_t)(row0 + fk)*H1D + u1];
    }

    // initial hidden states -> LDS fp32 (both read at t=0 from buffer 0)
    {
        const int u = tid & 127, br = tid >> 7;
        h0f[0][br][u] = h0i[(size_t)(row0 + br)*H0D + u];
    }
    if (tid < 256) {
        const int u = tid & 63, br = tid >> 6;
        h1q[0][br][u] = h1i[(size_t)(row0 + br)*H1D + u];
    }

    const int arow = fr >> 2;   // this lane's A-row batch index (rows duplicated x4)

    const float* xbase = x + ((size_t)row0 + arow)*IND + fk*8;
    f32x4 xa = {0,0,0,0}, xb = {0,0,0,0};
    if (prod) { xa = *(const f32x4*)xbase; xb = *(const f32x4*)(xbase + 4); }

    __syncthreads();

    const size_t H0O = (size_t)TS*BB*H1D;
    const size_t C0O = H0O + (size_t)BB*H0D;
    const size_t H1O = C0O + (size_t)BB*H0D;
    const size_t C1O = H1O + (size_t)BB*H1D;

    #pragma unroll 1
    for (int t = 0; t < TS; ++t) {
        const int rp = t & 1;
        // ========== Phase 1: layer0, step t (waves 0-3) ==========
        if (prod) {
            bf16x8 xf = cvt8(xa, xb);
            {   // prefetch x(t+1)
                const int tn = (t + 1 < TS) ? (t + 1) : t;
                const float* xp = xbase + (size_t)tn * (BB*IND);
                xa = *(const f32x4*)xp; xb = *(const f32x4*)(xp + 4);
            }
            bf16x8 hf[4];
            #pragma unroll
            for (int ks = 0; ks < 4; ++ks)
                hf[ks] = ld8(&h0f[rp][arow][ks*32 + fk*8]);

            #pragma unroll
            for (int sl = 0; sl < 2; ++sl) {
                const int u = (w + 4*sl)*16 + fr;
                f32x4 ag[5];
                #pragma unroll
                for (int g = 0; g < 4; ++g) {
                    const float b = BZ[sl*5 + g];
                    f32x4 a = {b, b, b, b};
                    a = mfma16(xf, WF[sl*21 + g*5], a);
                    #pragma unroll
                    for (int ks = 0; ks < 4; ++ks)
                        a = mfma16(hf[ks], WF[sl*21 + g*5 + 1 + ks], a);
                    ag[g] = a;
                }
                {
                    const float b = BZ[sl*5 + 4];
                    f32x4 a = {b, b, b, b};
                    ag[4] = mfma16(xf, WF[sl*21 + 20], a);
                }
                // lane's element: batch row fk (C row 4*fk -> reg 0)
                const float i_ = sigm(ag[0][0]);
                const float f_ = sigm(ag[1][0]);
                const float g_ = tanh_f(ag[2][0]);
                const float o_ = sigm(ag[3][0]);
                const float c  = fmaf(f_, CS[sl], i_ * g_);
                CS[sl] = c;
                const float hn = fmaf(o_, tanh_f(c), ag[4][0]);   // pre-clip state
                const float iv = fminf(fmaxf(hn, -10.f), 10.f);   // layer1 input
                h0f[rp ^ 1][fk][u] = hn;
                i1f[rp ^ 1][fk][u] = iv;
                if (t == TS - 1) {
                    out[H0O + (size_t)(row0 + fk)*H0D + u] = hn;
                    out[C0O + (size_t)(row0 + fk)*H0D + u] = c;
                }
            }
        }
        __syncthreads();   // B1: i1f[rp^1] ready for consumers

        // ========== Phase 2: layer1, SAME step t (waves 4-7) ==========
        if (!prod) {
            bf16x8 pf[4], hq[2];
            #pragma unroll
            for (int ks = 0; ks < 4; ++ks)
                pf[ks] = ld8(&i1f[rp ^ 1][arow][ks*32 + fk*8]);
            #pragma unroll
            for (int k2 = 0; k2 < 2; ++k2)
                hq[k2] = ld8(&h1q[rp][arow][k2*32 + fk*8]);

            const int u1 = (w - 4)*16 + fr;
            f32x4 a1[5];
            #pragma unroll
            for (int g = 0; g < 4; ++g) {
                const float b = BZ[g];
                f32x4 a = {b, b, b, b};
                #pragma unroll
                for (int ks = 0; ks < 4; ++ks)
                    a = mfma16(pf[ks], WF[g*6 + ks], a);
                #pragma unroll
                for (int k2 = 0; k2 < 2; ++k2)
                    a = mfma16(hq[k2], WF[g*6 + 4 + k2], a);
                a1[g] = a;
            }
            {
                const float b = BZ[4];
                f32x4 a = {b, b, b, b};
                #pragma unroll
                for (int ks = 0; ks < 4; ++ks)
                    a = mfma16(pf[ks], WF[24 + ks], a);
                a1[4] = a;
            }
            const float i_ = sigm(a1[0][0]);
            const float f_ = sigm(a1[1][0]);
            const float g_ = tanh_f(a1[2][0]);
            const float o_ = sigm(a1[3][0]);
            const float c  = fmaf(f_, CS[0], i_ * g_);
            CS[0] = c;
            const float hn = fmaf(o_, tanh_f(c), a1[4][0]);   // pre-clip state
            const float yv = fminf(fmaxf(hn, -10.f), 10.f);
            out[((size_t)t*BB + row0 + fk)*H1D + u1] = yv;
            h1q[rp ^ 1][fk][u1] = hn;
            if (t == TS - 1) {
                out[H1O + (size_t)(row0 + fk)*H1D + u1] = hn;
                out[C1O + (size_t)(row0 + fk)*H1D + u1] = c;
            }
        }
        __syncthreads();   // B2: protect h0f/i1f before next iteration's writes
    }
}

} // namespace

extern "C" void kernel_launch(void* const* d_in, const int* in_sizes, int n_in,
                              void* d_out, int out_size, void* d_ws, size_t ws_size,
                              hipStream_t stream) {
    (void)in_sizes; (void)n_in; (void)d_ws; (void)ws_size; (void)out_size;
    const float* x    = (const float*)d_in[0];
    const float* h0i  = (const float*)d_in[1];
    const float* c0i  = (const float*)d_in[2];
    const float* h1i  = (const float*)d_in[3];
    const float* c1i  = (const float*)d_in[4];
    const float* Wih0 = (const float*)d_in[5];
    const float* Whh0 = (const float*)d_in[6];
    const float* bih0 = (const float*)d_in[7];
    const float* bhh0 = (const float*)d_in[8];
    const float* Ws0  = (const float*)d_in[9];
    const float* bs0  = (const float*)d_in[10];
    const float* Wih1 = (const float*)d_in[11];
    const float* Whh1 = (const float*)d_in[12];
    const float* bih1 = (const float*)d_in[13];
    const float* bhh1 = (const float*)d_in[14];
    const float* Ws1  = (const float*)d_in[15];
    const float* bs1  = (const float*)d_in[16];

    resid_lstm<<<dim3(BB / RPW), dim3(512), 0, stream>>>(
        x, h0i, c0i, h1i, c1i,
        Wih0, Whh0, bih0, bhh0, Ws0, bs0,
        Wih1, Whh1, bih1, bhh1, Ws1, bs1,
        (float*)d_out);
}